// Round 1
// baseline (26.294 us; speedup 1.0000x reference)
//
#include <hip/hip_runtime.h>

// Problem constants (from the reference file)
#define SEQ   2048
#define DIM   1024
#define BATCH 8

// One block per sequence position s. 256 threads; each thread owns 4
// consecutive output floats (2 sin/cos pairs), looping over the 8 batch rows.
// PE trig is computed once per (s, d-pair) and reused across the batch.
__global__ __launch_bounds__(256) void embed_pe_kernel(
    const int* __restrict__ x,      // [BATCH, SEQ] int32 token ids
    const float* __restrict__ W,    // [VOCAB, DIM] fp32 embedding table
    float* __restrict__ out)        // [BATCH, SEQ, DIM] fp32
{
    const int s = blockIdx.x;       // 0..SEQ-1
    const int t = threadIdx.x;      // 0..255
    const int i0 = t * 2;           // pair index (d/2)
    const int d0 = t * 4;           // first of this thread's 4 floats

    // ang = s / 10000^(2i/D) = s * exp2(-i * 2*log2(10000)/D)
    const float kNegC = -0.025952563241307518f;   // -2*log2(10000)/1024
    const float fs = (float)s;
    const float ang0 = fs * exp2f(kNegC * (float)i0);
    const float ang1 = fs * exp2f(kNegC * (float)(i0 + 1));
    float s0, c0, s1, c1;
    sincosf(ang0, &s0, &c0);
    sincosf(ang1, &s1, &c1);

    #pragma unroll
    for (int b = 0; b < BATCH; ++b) {
        const int row = x[b * SEQ + s];           // block-uniform -> scalar load
        const float4 w = *reinterpret_cast<const float4*>(
            W + (size_t)row * DIM + d0);
        float4 o;
        o.x = w.x + s0;
        o.y = w.y + c0;
        o.z = w.z + s1;
        o.w = w.w + c1;
        *reinterpret_cast<float4*>(
            out + ((size_t)b * SEQ + s) * DIM + d0) = o;
    }
}

extern "C" void kernel_launch(void* const* d_in, const int* in_sizes, int n_in,
                              void* d_out, int out_size, void* d_ws, size_t ws_size,
                              hipStream_t stream) {
    const int*   x = (const int*)d_in[0];
    const float* W = (const float*)d_in[1];
    float* out = (float*)d_out;

    dim3 grid(SEQ);     // 2048 blocks
    dim3 block(256);
    embed_pe_kernel<<<grid, block, 0, stream>>>(x, W, out);
}